// Round 1
// baseline (1116.635 us; speedup 1.0000x reference)
//
#include <hip/hip_runtime.h>
#include <hip/hip_bf16.h>
#include <cstdint>

// ---------------------------------------------------------------------------
// Problem constants (from reference):
//   x: (4,192,192,256) f32; W_qkv: (256,768); b_qkv: (768,);
//   W_proj: (256,256); b_proj: (256,)
//   DIM=256 HEADS=8 HD=32 WS=(8,8) DS=(2,2) SH=(4,4) TW=(16,16) N=64
//   M = 4*192*192 = 147456 pixel rows; B_ = 2304 windows of 64 tokens.
// ---------------------------------------------------------------------------

static constexpr int MROWS = 147456;
static constexpr int KDIM  = 256;
static constexpr int QKVN  = 768;

// ============================================================
// fp32 tiled GEMM + bias: C[M,N] = A[M,K] @ B[K,N] + bias[N]
// 128x128 tile, BK=16, 256 threads, 8x8 per-thread microtile.
// M%128==0, N%128==0, K%16==0 guaranteed here.
// ============================================================
__global__ __launch_bounds__(256)
void gemm_bias_f32(const float* __restrict__ A, const float* __restrict__ B,
                   const float* __restrict__ bias, float* __restrict__ C,
                   int M, int N, int K)
{
    constexpr int TM = 128, TN = 128, BK = 16;
    __shared__ float As[BK][TM];   // A tile stored transposed: As[k][row]
    __shared__ float Bs[BK][TN];

    const int tid = threadIdx.x;
    const int bm = blockIdx.x * TM;
    const int bn = blockIdx.y * TN;
    const int tr = (tid >> 4) << 3;   // 0..120 step 8
    const int tc = (tid & 15) << 3;   // 0..120 step 8

    // A-load mapping: 128 rows x 16 cols = 512 float4; 2 per thread
    const int ar  = tid >> 1;          // row 0..127
    const int ac4 = (tid & 1) * 2;     // float4-slot 0 or 2 (covers k 0..7 / 8..15)
    // B-load mapping: 16 rows x 128 cols = 512 float4; 2 per thread
    const int br  = tid >> 5;          // 0..7 (and +8)
    const int bc4 = tid & 31;          // float4-slot along N

    float acc[8][8] = {};

    for (int k0 = 0; k0 < K; k0 += BK) {
        const float4 a0 = *(const float4*)(A + (size_t)(bm + ar) * K + k0 + ac4 * 4);
        const float4 a1 = *(const float4*)(A + (size_t)(bm + ar) * K + k0 + ac4 * 4 + 4);
        const float4 b0 = *(const float4*)(B + (size_t)(k0 + br) * N + bn + bc4 * 4);
        const float4 b1 = *(const float4*)(B + (size_t)(k0 + br + 8) * N + bn + bc4 * 4);
        __syncthreads();   // previous iteration's reads done
        As[ac4 * 4 + 0][ar] = a0.x;
        As[ac4 * 4 + 1][ar] = a0.y;
        As[ac4 * 4 + 2][ar] = a0.z;
        As[ac4 * 4 + 3][ar] = a0.w;
        As[ac4 * 4 + 4][ar] = a1.x;
        As[ac4 * 4 + 5][ar] = a1.y;
        As[ac4 * 4 + 6][ar] = a1.z;
        As[ac4 * 4 + 7][ar] = a1.w;
        *(float4*)&Bs[br][bc4 * 4]     = b0;
        *(float4*)&Bs[br + 8][bc4 * 4] = b1;
        __syncthreads();
        #pragma unroll
        for (int kk = 0; kk < BK; kk++) {
            float a[8], b[8];
            #pragma unroll
            for (int i = 0; i < 8; i++) a[i] = As[kk][tr + i];
            #pragma unroll
            for (int j = 0; j < 8; j++) b[j] = Bs[kk][tc + j];
            #pragma unroll
            for (int i = 0; i < 8; i++)
                #pragma unroll
                for (int j = 0; j < 8; j++)
                    acc[i][j] = fmaf(a[i], b[j], acc[i][j]);
        }
    }

    #pragma unroll
    for (int i = 0; i < 8; i++) {
        float4 o0 = make_float4(acc[i][0] + bias[bn + tc + 0],
                                acc[i][1] + bias[bn + tc + 1],
                                acc[i][2] + bias[bn + tc + 2],
                                acc[i][3] + bias[bn + tc + 3]);
        float4 o1 = make_float4(acc[i][4] + bias[bn + tc + 4],
                                acc[i][5] + bias[bn + tc + 5],
                                acc[i][6] + bias[bn + tc + 6],
                                acc[i][7] + bias[bn + tc + 7]);
        *(float4*)(C + (size_t)(bm + tr + i) * N + bn + tc)     = o0;
        *(float4*)(C + (size_t)(bm + tr + i) * N + bn + tc + 4) = o1;
    }
}

// ============================================================
// Windowed attention with 2D RoPE + analytic shift-mask.
// One block (64 threads = 1 wave) per (window b_, head).
// Thread n owns token row n of the window.
// Writes output already un-permuted + rolled into final
// spatial (b, h', w', c) order so proj GEMM is a plain GEMM.
// ============================================================
__global__ __launch_bounds__(64)
void attn_win(const float* __restrict__ qkv, float* __restrict__ out2)
{
    const int bid  = blockIdx.x;       // 0 .. 2304*8-1
    const int b_   = bid >> 3;
    const int head = bid & 7;
    const int n    = threadIdx.x;      // token 0..63
    const int wh   = n >> 3;           // row in 8x8 window grid
    const int wwp  = n & 7;            // col in 8x8 window grid

    __shared__ float ks[64][36];       // padded: row stride 144B (16B-aligned)
    __shared__ float vs[64][36];

    const float* row = qkv + (size_t)(b_ * 64 + n) * 768 + head * 32;

    float q[32], kreg[32];
    #pragma unroll
    for (int i = 0; i < 8; i++) {
        float4 t = *(const float4*)(row + i * 4);
        q[i*4+0] = t.x; q[i*4+1] = t.y; q[i*4+2] = t.z; q[i*4+3] = t.w;
    }
    #pragma unroll
    for (int i = 0; i < 8; i++) {
        float4 t = *(const float4*)(row + 256 + i * 4);
        kreg[i*4+0] = t.x; kreg[i*4+1] = t.y; kreg[i*4+2] = t.z; kreg[i*4+3] = t.w;
    }
    #pragma unroll
    for (int i = 0; i < 8; i++) {
        float4 t = *(const float4*)(row + 512 + i * 4);
        vs[n][i*4+0] = t.x; vs[n][i*4+1] = t.y; vs[n][i*4+2] = t.z; vs[n][i*4+3] = t.w;
    }

    // 2D RoPE: dims [0,16) rotated by wh-angles, [16,32) by ww-angles.
    // inv[j] = 10000^(-j/8) = exp(-j * ln(10000)/8)
    #pragma unroll
    for (int j = 0; j < 8; j++) {
        const float invj = __expf(-1.1512925464970231f * (float)j);
        float sH, cH, sW, cW;
        __sincosf((float)wh  * invj, &sH, &cH);
        __sincosf((float)wwp * invj, &sW, &cW);
        float u1, u2;
        u1 = q[j];      u2 = q[j + 8];   q[j]      = u1*cH - u2*sH;  q[j + 8]   = u1*sH + u2*cH;
        u1 = q[16 + j]; u2 = q[24 + j];  q[16 + j] = u1*cW - u2*sW;  q[24 + j]  = u1*sW + u2*cW;
        u1 = kreg[j];      u2 = kreg[j + 8];   kreg[j]      = u1*cH - u2*sH;  kreg[j + 8]  = u1*sH + u2*cH;
        u1 = kreg[16 + j]; u2 = kreg[24 + j];  kreg[16 + j] = u1*cW - u2*sW;  kreg[24 + j] = u1*sW + u2*cW;
    }
    #pragma unroll
    for (int d = 0; d < 32; d++) ks[n][d] = kreg[d];
    __syncthreads();

    // S = scale * q . k^T
    float s[64];
    const float scale = 0.17677669529663687f;  // 32^-0.5
    #pragma unroll
    for (int m = 0; m < 64; m++) {
        float acc = 0.f;
        #pragma unroll
        for (int d = 0; d < 32; d++) acc = fmaf(q[d], ks[m][d], acc);
        s[m] = acc * scale;
    }

    // Analytic shift-mask: only tiles in the last tile-row (bh==11 <=> wm>=528).
    // Class by window-grid row: wh<4 -> 0, wh in {4,5} -> 1, else 2.
    const int wm = b_ % 576;
    if (wm >= 528) {
        const int cn = (wh < 4) ? 0 : ((wh < 6) ? 1 : 2);
        #pragma unroll
        for (int m = 0; m < 64; m++) {
            const int mh = m >> 3;
            const int cm = (mh < 4) ? 0 : ((mh < 6) ? 1 : 2);
            if (cm != cn) s[m] = -1e30f;
        }
    }

    // softmax over the 64 per-lane scores
    float mx = s[0];
    #pragma unroll
    for (int m = 1; m < 64; m++) mx = fmaxf(mx, s[m]);
    float sum = 0.f;
    #pragma unroll
    for (int m = 0; m < 64; m++) { s[m] = __expf(s[m] - mx); sum += s[m]; }
    const float rsum = 1.f / sum;

    // O = P @ V
    float o[32] = {};
    #pragma unroll
    for (int m = 0; m < 64; m++) {
        const float p = s[m];
        #pragma unroll
        for (int d = 0; d < 32; d++) o[d] = fmaf(p, vs[m][d], o[d]);
    }

    // Un-permute + roll(4,4) into final spatial order.
    const int bw = b_ >> 2, ds = b_ & 3, dh = ds >> 1, dw = ds & 1;
    const int bimg = bw / 144;
    const int t144 = bw % 144;
    const int bh = t144 / 12, bwc = t144 % 12;
    int hp = bh * 16 + wh * 2 + dh + 4;  if (hp >= 192) hp -= 192;
    int wp = bwc * 16 + wwp * 2 + dw + 4; if (wp >= 192) wp -= 192;

    float* dst = out2 + ((size_t)(bimg * 192 + hp) * 192 + wp) * 256 + head * 32;
    #pragma unroll
    for (int i = 0; i < 8; i++) {
        *(float4*)(dst + i * 4) = make_float4(o[i*4+0]*rsum, o[i*4+1]*rsum,
                                              o[i*4+2]*rsum, o[i*4+3]*rsum);
    }
}

// ============================================================
extern "C" void kernel_launch(void* const* d_in, const int* in_sizes, int n_in,
                              void* d_out, int out_size, void* d_ws, size_t ws_size,
                              hipStream_t stream)
{
    const float* x      = (const float*)d_in[0];
    const float* W_qkv  = (const float*)d_in[1];
    const float* b_qkv  = (const float*)d_in[2];
    const float* W_proj = (const float*)d_in[3];
    const float* b_proj = (const float*)d_in[4];
    float* out = (float*)d_out;

    // workspace layout: qkv (147456*768 f32) | attn-out in final order (147456*256 f32)
    float* qkv  = (float*)d_ws;
    float* buf2 = qkv + (size_t)MROWS * QKVN;

    // 1) QKV GEMM
    {
        dim3 grid(MROWS / 128, QKVN / 128);
        gemm_bias_f32<<<grid, 256, 0, stream>>>(x, W_qkv, b_qkv, qkv, MROWS, QKVN, KDIM);
    }
    // 2) windowed attention (+RoPE, +mask, +un-permute, +roll)
    {
        attn_win<<<2304 * 8, 64, 0, stream>>>(qkv, buf2);
    }
    // 3) projection GEMM
    {
        dim3 grid(MROWS / 128, KDIM / 128);
        gemm_bias_f32<<<grid, 256, 0, stream>>>(buf2, W_proj, b_proj, out, MROWS, KDIM, KDIM);
    }
}

// Round 2
// 570.814 us; speedup vs baseline: 1.9562x; 1.9562x over previous
//
#include <hip/hip_runtime.h>
#include <hip/hip_bf16.h>
#include <cstdint>

static constexpr int MROWS = 147456;
static constexpr int KDIM  = 256;
static constexpr int QKVN  = 768;

typedef __bf16 bf16x8 __attribute__((ext_vector_type(8)));
typedef float  f32x4  __attribute__((ext_vector_type(4)));

static __device__ __forceinline__ uint16_t f2bf(float f) {
    uint32_t x = __float_as_uint(f);
    x += 0x7FFFu + ((x >> 16) & 1u);   // RNE
    return (uint16_t)(x >> 16);
}
static __device__ __forceinline__ float bl(uint32_t u) { return __uint_as_float(u << 16); }
static __device__ __forceinline__ float bh(uint32_t u) { return __uint_as_float(u & 0xffff0000u); }
static __device__ __forceinline__ uint32_t pack2(float a, float b) {
    return (uint32_t)f2bf(a) | ((uint32_t)f2bf(b) << 16);
}

// ============================================================
// fp32 -> bf16 bulk convert (x)
// ============================================================
__global__ void cvt_f32_bf16_k(const float* __restrict__ in, uint16_t* __restrict__ out, int n4)
{
    int i = blockIdx.x * blockDim.x + threadIdx.x;
    const int stride = gridDim.x * blockDim.x;
    for (; i < n4; i += stride) {
        float4 v = ((const float4*)in)[i];
        uint2 o;
        o.x = pack2(v.x, v.y);
        o.y = pack2(v.z, v.w);
        ((uint2*)out)[i] = o;
    }
}

// Wt[n][k] = bf16(W[k][n])   (W is [K][N] row-major fp32)
__global__ void transpose_cvt_k(const float* __restrict__ W, uint16_t* __restrict__ Wt, int K, int N)
{
    int id = blockIdx.x * blockDim.x + threadIdx.x;
    if (id >= K * N) return;
    int n = id / K, k = id - n * K;
    Wt[id] = f2bf(W[(size_t)k * N + n]);
}

// ============================================================
// bf16 MFMA GEMM: C[M,N] = A[M,K] @ Bt[N,K]^T + bias
// 128x128 tile, BK=32, 4 waves (each 64x64 = 4x4 16x16 frags),
// global_load_lds width-16 staging with XOR k-chunk swizzle.
// ============================================================
template<int OUT_BF16>
__global__ __launch_bounds__(256)
void gemm_bf16(const uint16_t* __restrict__ A, const uint16_t* __restrict__ Bt,
               const float* __restrict__ bias, void* __restrict__ Cout,
               int M, int N, int K, int ntn)
{
    __shared__ __align__(16) uint16_t lds[2][2][128 * 32];

    const int tid = threadIdx.x;
    const int wv = tid >> 6, ln = tid & 63;

    // bijective XCD swizzle (nwg % 8 == 0 for all our launches)
    const int nwg = gridDim.x;
    const int q8 = nwg >> 3;
    const int sw = (blockIdx.x & 7) * q8 + (blockIdx.x >> 3);
    const int bm = (sw / ntn) * 128;
    const int bn = (sw - (sw / ntn) * ntn) * 128;

    const uint16_t* Ab = A + (size_t)bm * K;
    const uint16_t* Bb = Bt + (size_t)bn * K;

    const int wr = (wv >> 1) * 64;   // wave sub-tile origin
    const int wc = (wv & 1) * 64;
    const int frow = ln & 15;
    const int kb = (ln >> 4) * 16;   // byte offset of this lane's k-chunk

    f32x4 acc[4][4] = {};

    auto stage = [&](int buf, int k0) {
        #pragma unroll
        for (int it = 0; it < 2; ++it) {
            const int c = it * 256 + wv * 64 + ln;
            const int row = c >> 2, kl = c & 3;
            const int ks = kl ^ ((row ^ (row >> 2)) & 3);   // involution swizzle
            const uint16_t* srcA = Ab + row * K + k0 + ks * 8;
            const uint16_t* srcB = Bb + row * K + k0 + ks * 8;
            uint16_t* dA = &lds[buf][0][(size_t)(it * 256 + wv * 64) * 8];
            uint16_t* dB = &lds[buf][1][(size_t)(it * 256 + wv * 64) * 8];
            __builtin_amdgcn_global_load_lds((const __attribute__((address_space(1))) void*)srcA,
                                             (__attribute__((address_space(3))) void*)dA, 16, 0, 0);
            __builtin_amdgcn_global_load_lds((const __attribute__((address_space(1))) void*)srcB,
                                             (__attribute__((address_space(3))) void*)dB, 16, 0, 0);
        }
    };

    stage(0, 0);
    const int nt = K / 32;
    for (int t = 0; t < nt; ++t) {
        const int cur = t & 1;
        __syncthreads();
        if (t + 1 < nt) stage(cur ^ 1, (t + 1) * 32);
        bf16x8 af[4], bfr[4];
        #pragma unroll
        for (int i = 0; i < 4; ++i) {
            const int rA = wr + i * 16 + frow;
            const int offA = (rA * 64 + kb) ^ (((rA ^ (rA >> 2)) & 3) << 4);
            af[i] = *(const bf16x8*)((const char*)&lds[cur][0][0] + offA);
            const int rB = wc + i * 16 + frow;
            const int offB = (rB * 64 + kb) ^ (((rB ^ (rB >> 2)) & 3) << 4);
            bfr[i] = *(const bf16x8*)((const char*)&lds[cur][1][0] + offB);
        }
        #pragma unroll
        for (int i = 0; i < 4; ++i)
            #pragma unroll
            for (int j = 0; j < 4; ++j)
                acc[i][j] = __builtin_amdgcn_mfma_f32_16x16x32_bf16(af[i], bfr[j], acc[i][j], 0, 0, 0);
    }

    // epilogue: C/D layout col=lane&15, row=(lane>>4)*4+reg
    const int r4 = (ln >> 4) * 4;
    #pragma unroll
    for (int i = 0; i < 4; ++i) {
        #pragma unroll
        for (int j = 0; j < 4; ++j) {
            const int col = bn + wc + j * 16 + frow;
            const float bs = bias[col];
            #pragma unroll
            for (int r = 0; r < 4; ++r) {
                const int row = bm + wr + i * 16 + r4 + r;
                const float v = acc[i][j][r] + bs;
                if (OUT_BF16) ((uint16_t*)Cout)[(size_t)row * N + col] = f2bf(v);
                else          ((float*)Cout)[(size_t)row * N + col]    = v;
            }
        }
    }
}

// ============================================================
// Windowed attention (bf16 in/out) + 2D RoPE + analytic mask
// + fused un-permute/roll. One wave per (window, head).
// ============================================================
__global__ __launch_bounds__(64)
void attn_win(const uint16_t* __restrict__ qkv, uint16_t* __restrict__ out2)
{
    const int bid  = blockIdx.x;
    const int b_   = bid >> 3;
    const int head = bid & 7;
    const int n    = threadIdx.x;
    const int wh   = n >> 3;
    const int wwp  = n & 7;

    __shared__ float ks[64][36];
    __shared__ float vs[64][36];

    const uint16_t* rowp = qkv + (size_t)(b_ * 64 + n) * 768 + head * 32;

    float q[32], kreg[32];
    #pragma unroll
    for (int i = 0; i < 4; ++i) {
        uint4 t = *(const uint4*)(rowp + i * 8);
        q[i*8+0] = bl(t.x); q[i*8+1] = bh(t.x);
        q[i*8+2] = bl(t.y); q[i*8+3] = bh(t.y);
        q[i*8+4] = bl(t.z); q[i*8+5] = bh(t.z);
        q[i*8+6] = bl(t.w); q[i*8+7] = bh(t.w);
    }
    #pragma unroll
    for (int i = 0; i < 4; ++i) {
        uint4 t = *(const uint4*)(rowp + 256 + i * 8);
        kreg[i*8+0] = bl(t.x); kreg[i*8+1] = bh(t.x);
        kreg[i*8+2] = bl(t.y); kreg[i*8+3] = bh(t.y);
        kreg[i*8+4] = bl(t.z); kreg[i*8+5] = bh(t.z);
        kreg[i*8+6] = bl(t.w); kreg[i*8+7] = bh(t.w);
    }
    #pragma unroll
    for (int i = 0; i < 4; ++i) {
        uint4 t = *(const uint4*)(rowp + 512 + i * 8);
        vs[n][i*8+0] = bl(t.x); vs[n][i*8+1] = bh(t.x);
        vs[n][i*8+2] = bl(t.y); vs[n][i*8+3] = bh(t.y);
        vs[n][i*8+4] = bl(t.z); vs[n][i*8+5] = bh(t.z);
        vs[n][i*8+6] = bl(t.w); vs[n][i*8+7] = bh(t.w);
    }

    // 2D RoPE
    #pragma unroll
    for (int j = 0; j < 8; ++j) {
        const float invj = __expf(-1.1512925464970231f * (float)j);
        float sH, cH, sW, cW;
        __sincosf((float)wh  * invj, &sH, &cH);
        __sincosf((float)wwp * invj, &sW, &cW);
        float u1, u2;
        u1 = q[j];      u2 = q[j + 8];   q[j]      = u1*cH - u2*sH;  q[j + 8]   = u1*sH + u2*cH;
        u1 = q[16 + j]; u2 = q[24 + j];  q[16 + j] = u1*cW - u2*sW;  q[24 + j]  = u1*sW + u2*cW;
        u1 = kreg[j];      u2 = kreg[j + 8];   kreg[j]      = u1*cH - u2*sH;  kreg[j + 8]  = u1*sH + u2*cH;
        u1 = kreg[16 + j]; u2 = kreg[24 + j];  kreg[16 + j] = u1*cW - u2*sW;  kreg[24 + j] = u1*sW + u2*cW;
    }
    #pragma unroll
    for (int d = 0; d < 32; ++d) ks[n][d] = kreg[d];
    __syncthreads();

    float s[64];
    const float scale = 0.17677669529663687f;
    #pragma unroll
    for (int m = 0; m < 64; ++m) {
        float acc = 0.f;
        #pragma unroll
        for (int d = 0; d < 32; ++d) acc = fmaf(q[d], ks[m][d], acc);
        s[m] = acc * scale;
    }

    const int wm = b_ % 576;
    if (wm >= 528) {
        const int cn = (wh < 4) ? 0 : ((wh < 6) ? 1 : 2);
        #pragma unroll
        for (int m = 0; m < 64; ++m) {
            const int mh = m >> 3;
            const int cm = (mh < 4) ? 0 : ((mh < 6) ? 1 : 2);
            if (cm != cn) s[m] = -1e30f;
        }
    }

    float mx = s[0];
    #pragma unroll
    for (int m = 1; m < 64; ++m) mx = fmaxf(mx, s[m]);
    float sum = 0.f;
    #pragma unroll
    for (int m = 0; m < 64; ++m) { s[m] = __expf(s[m] - mx); sum += s[m]; }
    const float rsum = 1.f / sum;

    float o[32] = {};
    #pragma unroll
    for (int m = 0; m < 64; ++m) {
        const float p = s[m];
        #pragma unroll
        for (int d = 0; d < 32; ++d) o[d] = fmaf(p, vs[m][d], o[d]);
    }

    const int bw = b_ >> 2, ds = b_ & 3, dh = ds >> 1, dw = ds & 1;
    const int bimg = bw / 144;
    const int t144 = bw % 144;
    const int bh = t144 / 12, bwc = t144 % 12;
    int hp = bh * 16 + wh * 2 + dh + 4;  if (hp >= 192) hp -= 192;
    int wp = bwc * 16 + wwp * 2 + dw + 4; if (wp >= 192) wp -= 192;

    uint16_t* dst = out2 + ((size_t)(bimg * 192 + hp) * 192 + wp) * 256 + head * 32;
    #pragma unroll
    for (int i = 0; i < 4; ++i) {
        uint4 t;
        t.x = pack2(o[i*8+0]*rsum, o[i*8+1]*rsum);
        t.y = pack2(o[i*8+2]*rsum, o[i*8+3]*rsum);
        t.z = pack2(o[i*8+4]*rsum, o[i*8+5]*rsum);
        t.w = pack2(o[i*8+6]*rsum, o[i*8+7]*rsum);
        *(uint4*)(dst + i * 8) = t;
    }
}

// ============================================================
extern "C" void kernel_launch(void* const* d_in, const int* in_sizes, int n_in,
                              void* d_out, int out_size, void* d_ws, size_t ws_size,
                              hipStream_t stream)
{
    const float* x      = (const float*)d_in[0];
    const float* W_qkv  = (const float*)d_in[1];
    const float* b_qkv  = (const float*)d_in[2];
    const float* W_proj = (const float*)d_in[3];
    const float* b_proj = (const float*)d_in[4];
    float* out = (float*)d_out;

    // workspace layout (all bf16 / uint16_t)
    uint16_t* xb   = (uint16_t*)d_ws;                 // 147456*256
    uint16_t* qkvb = xb   + (size_t)MROWS * KDIM;     // 147456*768
    uint16_t* bufb = qkvb + (size_t)MROWS * QKVN;     // 147456*256
    uint16_t* wtq  = bufb + (size_t)MROWS * KDIM;     // 768*256
    uint16_t* wtp  = wtq  + (size_t)QKVN * KDIM;      // 256*256

    // 1) converts
    cvt_f32_bf16_k<<<2048, 256, 0, stream>>>(x, xb, MROWS * KDIM / 4);
    transpose_cvt_k<<<(KDIM * QKVN + 255) / 256, 256, 0, stream>>>(W_qkv, wtq, KDIM, QKVN);
    transpose_cvt_k<<<(KDIM * KDIM + 255) / 256, 256, 0, stream>>>(W_proj, wtp, KDIM, KDIM);

    // 2) QKV GEMM (bf16 out)
    gemm_bf16<1><<<(MROWS / 128) * (QKVN / 128), 256, 0, stream>>>(
        xb, wtq, b_qkv, qkvb, MROWS, QKVN, KDIM, QKVN / 128);

    // 3) windowed attention
    attn_win<<<2304 * 8, 64, 0, stream>>>(qkvb, bufb);

    // 4) projection GEMM (fp32 out)
    gemm_bf16<0><<<(MROWS / 128) * (KDIM / 128), 256, 0, stream>>>(
        bufb, wtp, b_proj, out, MROWS, KDIM, KDIM, KDIM / 128);
}

// Round 3
// 344.099 us; speedup vs baseline: 3.2451x; 1.6589x over previous
//
#include <hip/hip_runtime.h>
#include <hip/hip_bf16.h>
#include <cstdint>

static constexpr int MROWS = 147456;
static constexpr int KDIM  = 256;
static constexpr int QKVN  = 768;

typedef __bf16 bf16x8 __attribute__((ext_vector_type(8)));
typedef float  f32x4  __attribute__((ext_vector_type(4)));

static __device__ __forceinline__ uint16_t f2bf(float f) {
    uint32_t x = __float_as_uint(f);
    x += 0x7FFFu + ((x >> 16) & 1u);   // RNE
    return (uint16_t)(x >> 16);
}
static __device__ __forceinline__ float bl(uint32_t u) { return __uint_as_float(u << 16); }
static __device__ __forceinline__ float bh(uint32_t u) { return __uint_as_float(u & 0xffff0000u); }
static __device__ __forceinline__ uint32_t pack2(float a, float b) {
    return (uint32_t)f2bf(a) | ((uint32_t)f2bf(b) << 16);
}

// ============================================================
// fp32 -> bf16 bulk convert (x)
// ============================================================
__global__ void cvt_f32_bf16_k(const float* __restrict__ in, uint16_t* __restrict__ out, int n4)
{
    int i = blockIdx.x * blockDim.x + threadIdx.x;
    const int stride = gridDim.x * blockDim.x;
    for (; i < n4; i += stride) {
        float4 v = ((const float4*)in)[i];
        uint2 o;
        o.x = pack2(v.x, v.y);
        o.y = pack2(v.z, v.w);
        ((uint2*)out)[i] = o;
    }
}

// Wt[n][k] = bf16(W[k][n])   (W is [K][N] row-major fp32)
__global__ void transpose_cvt_k(const float* __restrict__ W, uint16_t* __restrict__ Wt, int K, int N)
{
    int id = blockIdx.x * blockDim.x + threadIdx.x;
    if (id >= K * N) return;
    int n = id / K, k = id - n * K;
    Wt[id] = f2bf(W[(size_t)k * N + n]);
}

// ============================================================
// bf16 MFMA GEMM: C[M,N] = A[M,K] @ Bt[N,K]^T + bias
// 128x128 tile, BK=32, 4 waves, global_load_lds width-16.
// ============================================================
template<int OUT_BF16>
__global__ __launch_bounds__(256)
void gemm_bf16(const uint16_t* __restrict__ A, const uint16_t* __restrict__ Bt,
               const float* __restrict__ bias, void* __restrict__ Cout,
               int M, int N, int K, int ntn)
{
    __shared__ __align__(16) uint16_t lds[2][2][128 * 32];

    const int tid = threadIdx.x;
    const int wv = tid >> 6, ln = tid & 63;

    const int nwg = gridDim.x;
    const int q8 = nwg >> 3;
    const int sw = (blockIdx.x & 7) * q8 + (blockIdx.x >> 3);
    const int bm = (sw / ntn) * 128;
    const int bn = (sw - (sw / ntn) * ntn) * 128;

    const uint16_t* Ab = A + (size_t)bm * K;
    const uint16_t* Bb = Bt + (size_t)bn * K;

    const int wr = (wv >> 1) * 64;
    const int wc = (wv & 1) * 64;
    const int frow = ln & 15;
    const int kb = (ln >> 4) * 16;

    f32x4 acc[4][4] = {};

    auto stage = [&](int buf, int k0) {
        #pragma unroll
        for (int it = 0; it < 2; ++it) {
            const int c = it * 256 + wv * 64 + ln;
            const int row = c >> 2, kl = c & 3;
            const int ks = kl ^ ((row ^ (row >> 2)) & 3);
            const uint16_t* srcA = Ab + row * K + k0 + ks * 8;
            const uint16_t* srcB = Bb + row * K + k0 + ks * 8;
            uint16_t* dA = &lds[buf][0][(size_t)(it * 256 + wv * 64) * 8];
            uint16_t* dB = &lds[buf][1][(size_t)(it * 256 + wv * 64) * 8];
            __builtin_amdgcn_global_load_lds((const __attribute__((address_space(1))) void*)srcA,
                                             (__attribute__((address_space(3))) void*)dA, 16, 0, 0);
            __builtin_amdgcn_global_load_lds((const __attribute__((address_space(1))) void*)srcB,
                                             (__attribute__((address_space(3))) void*)dB, 16, 0, 0);
        }
    };

    stage(0, 0);
    const int nt = K / 32;
    for (int t = 0; t < nt; ++t) {
        const int cur = t & 1;
        __syncthreads();
        if (t + 1 < nt) stage(cur ^ 1, (t + 1) * 32);
        bf16x8 af[4], bfr[4];
        #pragma unroll
        for (int i = 0; i < 4; ++i) {
            const int rA = wr + i * 16 + frow;
            const int offA = (rA * 64 + kb) ^ (((rA ^ (rA >> 2)) & 3) << 4);
            af[i] = *(const bf16x8*)((const char*)&lds[cur][0][0] + offA);
            const int rB = wc + i * 16 + frow;
            const int offB = (rB * 64 + kb) ^ (((rB ^ (rB >> 2)) & 3) << 4);
            bfr[i] = *(const bf16x8*)((const char*)&lds[cur][1][0] + offB);
        }
        #pragma unroll
        for (int i = 0; i < 4; ++i)
            #pragma unroll
            for (int j = 0; j < 4; ++j)
                acc[i][j] = __builtin_amdgcn_mfma_f32_16x16x32_bf16(af[i], bfr[j], acc[i][j], 0, 0, 0);
    }

    const int r4 = (ln >> 4) * 4;
    #pragma unroll
    for (int i = 0; i < 4; ++i) {
        #pragma unroll
        for (int j = 0; j < 4; ++j) {
            const int col = bn + wc + j * 16 + frow;
            const float bs = bias[col];
            #pragma unroll
            for (int r = 0; r < 4; ++r) {
                const int row = bm + wr + i * 16 + r4 + r;
                const float v = acc[i][j][r] + bs;
                if (OUT_BF16) ((uint16_t*)Cout)[(size_t)row * N + col] = f2bf(v);
                else          ((float*)Cout)[(size_t)row * N + col]    = v;
            }
        }
    }
}

// ============================================================
// MFMA windowed attention. One wave per (window, head).
//   QK^T: 16 x mfma_16x16x32 (K = d = 32, exactly one per tile)
//   PV:   16 x mfma_16x16x32 (K = 64 tokens, 2 chained per tile)
// LDS (uint16 units):
//   Q [64][40] @ 0      (stride 80B, conflict-light)
//   K [64][40] @ 2560
//   VT[32][72] @ 5120   (V transposed: row=d, col=token)
//   P [64][72] @ 0      (overwrites Q/K after QK frags consumed)
//   O [64][40] @ 0      (overwrites P after P frags consumed)
// Softmax without max-subtract (|S| small; masked p := 0).
// ============================================================
__global__ __launch_bounds__(64)
void attn_win_mfma(const uint16_t* __restrict__ qkv, uint16_t* __restrict__ out2)
{
    __shared__ __align__(16) uint16_t lds[7424];

    const int bid  = blockIdx.x;
    const int b_   = bid >> 3;
    const int head = bid & 7;
    const int n    = threadIdx.x;       // token / lane
    const int wh   = n >> 3;
    const int wwp  = n & 7;
    const int frow = n & 15;
    const int hi4  = n >> 4;            // 0..3
    const int fk   = hi4 * 8;           // k-chunk elem offset
    const int r4   = hi4 * 4;           // C/D row group

    const uint16_t* rowp = qkv + (size_t)(b_ * 64 + n) * 768 + head * 32;

    // ---- load q, k (fp32) and v (raw bf16) ----
    float q[32], kr[32];
    uint4 vraw[4];
    #pragma unroll
    for (int i = 0; i < 4; ++i) {
        uint4 t = *(const uint4*)(rowp + i * 8);
        q[i*8+0] = bl(t.x); q[i*8+1] = bh(t.x);
        q[i*8+2] = bl(t.y); q[i*8+3] = bh(t.y);
        q[i*8+4] = bl(t.z); q[i*8+5] = bh(t.z);
        q[i*8+6] = bl(t.w); q[i*8+7] = bh(t.w);
    }
    #pragma unroll
    for (int i = 0; i < 4; ++i) {
        uint4 t = *(const uint4*)(rowp + 256 + i * 8);
        kr[i*8+0] = bl(t.x); kr[i*8+1] = bh(t.x);
        kr[i*8+2] = bl(t.y); kr[i*8+3] = bh(t.y);
        kr[i*8+4] = bl(t.z); kr[i*8+5] = bh(t.z);
        kr[i*8+6] = bl(t.w); kr[i*8+7] = bh(t.w);
    }
    #pragma unroll
    for (int i = 0; i < 4; ++i) vraw[i] = *(const uint4*)(rowp + 512 + i * 8);

    // ---- 2D RoPE (fold SCALE into q) ----
    const float SCALE = 0.17677669529663687f;
    #pragma unroll
    for (int j = 0; j < 8; ++j) {
        const float invj = __expf(-1.1512925464970231f * (float)j);
        float sH, cH, sW, cW;
        __sincosf((float)wh  * invj, &sH, &cH);
        __sincosf((float)wwp * invj, &sW, &cW);
        float u1, u2;
        u1 = q[j];      u2 = q[j + 8];   q[j]      = u1*cH - u2*sH;  q[j + 8]   = u1*sH + u2*cH;
        u1 = q[16 + j]; u2 = q[24 + j];  q[16 + j] = u1*cW - u2*sW;  q[24 + j]  = u1*sW + u2*cW;
        u1 = kr[j];      u2 = kr[j + 8];   kr[j]      = u1*cH - u2*sH;  kr[j + 8]  = u1*sH + u2*cH;
        u1 = kr[16 + j]; u2 = kr[24 + j];  kr[16 + j] = u1*cW - u2*sW;  kr[24 + j] = u1*sW + u2*cW;
    }

    // ---- stage Q, K rows; V transposed ----
    #pragma unroll
    for (int i = 0; i < 4; ++i) {
        uint4 t;
        t.x = pack2(q[i*8+0]*SCALE, q[i*8+1]*SCALE);
        t.y = pack2(q[i*8+2]*SCALE, q[i*8+3]*SCALE);
        t.z = pack2(q[i*8+4]*SCALE, q[i*8+5]*SCALE);
        t.w = pack2(q[i*8+6]*SCALE, q[i*8+7]*SCALE);
        *(uint4*)&lds[n * 40 + i * 8] = t;
        uint4 u;
        u.x = pack2(kr[i*8+0], kr[i*8+1]);
        u.y = pack2(kr[i*8+2], kr[i*8+3]);
        u.z = pack2(kr[i*8+4], kr[i*8+5]);
        u.w = pack2(kr[i*8+6], kr[i*8+7]);
        *(uint4*)&lds[2560 + n * 40 + i * 8] = u;
    }
    #pragma unroll
    for (int i = 0; i < 4; ++i) {
        lds[5120 + (i*8+0) * 72 + n] = (uint16_t)(vraw[i].x & 0xffff);
        lds[5120 + (i*8+1) * 72 + n] = (uint16_t)(vraw[i].x >> 16);
        lds[5120 + (i*8+2) * 72 + n] = (uint16_t)(vraw[i].y & 0xffff);
        lds[5120 + (i*8+3) * 72 + n] = (uint16_t)(vraw[i].y >> 16);
        lds[5120 + (i*8+4) * 72 + n] = (uint16_t)(vraw[i].z & 0xffff);
        lds[5120 + (i*8+5) * 72 + n] = (uint16_t)(vraw[i].z >> 16);
        lds[5120 + (i*8+6) * 72 + n] = (uint16_t)(vraw[i].w & 0xffff);
        lds[5120 + (i*8+7) * 72 + n] = (uint16_t)(vraw[i].w >> 16);
    }
    __syncthreads();

    // ---- QK^T: S[i][j], q-row = 16i + r4 + r, k-col = 16j + frow ----
    bf16x8 qf[4], kf[4];
    #pragma unroll
    for (int i = 0; i < 4; ++i) {
        qf[i] = *(const bf16x8*)&lds[(16 * i + frow) * 40 + fk];
        kf[i] = *(const bf16x8*)&lds[2560 + (16 * i + frow) * 40 + fk];
    }
    f32x4 s[4][4] = {};
    #pragma unroll
    for (int i = 0; i < 4; ++i)
        #pragma unroll
        for (int j = 0; j < 4; ++j)
            s[i][j] = __builtin_amdgcn_mfma_f32_16x16x32_bf16(qf[i], kf[j], s[i][j], 0, 0, 0);

    // ---- exp (no max-subtract), analytic mask, row-sum ----
    float p[4][4][4];
    #pragma unroll
    for (int i = 0; i < 4; ++i)
        #pragma unroll
        for (int j = 0; j < 4; ++j)
            #pragma unroll
            for (int r = 0; r < 4; ++r)
                p[i][j][r] = __expf(s[i][j][r]);

    const int wm = b_ % 576;
    if (wm >= 528) {
        int kc[4];
        #pragma unroll
        for (int j = 0; j < 4; ++j) {
            const int kh = (16 * j + frow) >> 3;
            kc[j] = (kh < 4) ? 0 : ((kh < 6) ? 1 : 2);
        }
        #pragma unroll
        for (int i = 0; i < 4; ++i)
            #pragma unroll
            for (int r = 0; r < 4; ++r) {
                const int qh = (16 * i + r4 + r) >> 3;
                const int qc = (qh < 4) ? 0 : ((qh < 6) ? 1 : 2);
                #pragma unroll
                for (int j = 0; j < 4; ++j)
                    if (kc[j] != qc) p[i][j][r] = 0.f;
            }
    }

    float rinv[4][4];
    #pragma unroll
    for (int i = 0; i < 4; ++i)
        #pragma unroll
        for (int r = 0; r < 4; ++r) {
            float sum = p[i][0][r] + p[i][1][r] + p[i][2][r] + p[i][3][r];
            sum += __shfl_xor(sum, 1);
            sum += __shfl_xor(sum, 2);
            sum += __shfl_xor(sum, 4);
            sum += __shfl_xor(sum, 8);
            rinv[i][r] = 1.f / sum;
        }

    // ---- P -> LDS bf16 (overwrite Q/K region) ----
    __syncthreads();
    #pragma unroll
    for (int i = 0; i < 4; ++i)
        #pragma unroll
        for (int r = 0; r < 4; ++r)
            #pragma unroll
            for (int j = 0; j < 4; ++j)
                lds[(16 * i + r4 + r) * 72 + 16 * j + frow] = f2bf(p[i][j][r]);
    __syncthreads();

    // ---- PV: O[i][jv], K-dim = 64 tokens (2 chained MFMAs) ----
    bf16x8 pf[4][2], vf[2][2];
    #pragma unroll
    for (int i = 0; i < 4; ++i)
        #pragma unroll
        for (int kc = 0; kc < 2; ++kc)
            pf[i][kc] = *(const bf16x8*)&lds[(16 * i + frow) * 72 + kc * 32 + fk];
    #pragma unroll
    for (int jv = 0; jv < 2; ++jv)
        #pragma unroll
        for (int kc = 0; kc < 2; ++kc)
            vf[jv][kc] = *(const bf16x8*)&lds[5120 + (16 * jv + frow) * 72 + kc * 32 + fk];

    f32x4 o[4][2] = {};
    #pragma unroll
    for (int i = 0; i < 4; ++i)
        #pragma unroll
        for (int jv = 0; jv < 2; ++jv) {
            o[i][jv] = __builtin_amdgcn_mfma_f32_16x16x32_bf16(pf[i][0], vf[jv][0], o[i][jv], 0, 0, 0);
            o[i][jv] = __builtin_amdgcn_mfma_f32_16x16x32_bf16(pf[i][1], vf[jv][1], o[i][jv], 0, 0, 0);
        }

    // ---- O -> LDS (normalized, bf16, token-major) ----
    __syncthreads();
    #pragma unroll
    for (int i = 0; i < 4; ++i)
        #pragma unroll
        for (int jv = 0; jv < 2; ++jv)
            #pragma unroll
            for (int r = 0; r < 4; ++r)
                lds[(16 * i + r4 + r) * 40 + 16 * jv + frow] = f2bf(o[i][jv][r] * rinv[i][r]);
    __syncthreads();

    // ---- coalesced store with fused un-permute + roll ----
    const int bw = b_ >> 2, ds = b_ & 3, dh = ds >> 1, dw = ds & 1;
    const int bimg = bw / 144;
    const int t144 = bw % 144;
    const int bh = t144 / 12, bwc = t144 % 12;
    int hp = bh * 16 + wh * 2 + dh + 4;  if (hp >= 192) hp -= 192;
    int wp = bwc * 16 + wwp * 2 + dw + 4; if (wp >= 192) wp -= 192;

    uint16_t* dst = out2 + ((size_t)(bimg * 192 + hp) * 192 + wp) * 256 + head * 32;
    #pragma unroll
    for (int i = 0; i < 4; ++i)
        *(uint4*)(dst + i * 8) = *(const uint4*)&lds[n * 40 + i * 8];
}

// ============================================================
extern "C" void kernel_launch(void* const* d_in, const int* in_sizes, int n_in,
                              void* d_out, int out_size, void* d_ws, size_t ws_size,
                              hipStream_t stream)
{
    const float* x      = (const float*)d_in[0];
    const float* W_qkv  = (const float*)d_in[1];
    const float* b_qkv  = (const float*)d_in[2];
    const float* W_proj = (const float*)d_in[3];
    const float* b_proj = (const float*)d_in[4];
    float* out = (float*)d_out;

    uint16_t* xb   = (uint16_t*)d_ws;                 // 147456*256
    uint16_t* qkvb = xb   + (size_t)MROWS * KDIM;     // 147456*768
    uint16_t* bufb = qkvb + (size_t)MROWS * QKVN;     // 147456*256
    uint16_t* wtq  = bufb + (size_t)MROWS * KDIM;     // 768*256
    uint16_t* wtp  = wtq  + (size_t)QKVN * KDIM;      // 256*256

    cvt_f32_bf16_k<<<2048, 256, 0, stream>>>(x, xb, MROWS * KDIM / 4);
    transpose_cvt_k<<<(KDIM * QKVN + 255) / 256, 256, 0, stream>>>(W_qkv, wtq, KDIM, QKVN);
    transpose_cvt_k<<<(KDIM * KDIM + 255) / 256, 256, 0, stream>>>(W_proj, wtp, KDIM, KDIM);

    gemm_bf16<1><<<(MROWS / 128) * (QKVN / 128), 256, 0, stream>>>(
        xb, wtq, b_qkv, qkvb, MROWS, QKVN, KDIM, QKVN / 128);

    attn_win_mfma<<<2304 * 8, 64, 0, stream>>>(qkvb, bufb);

    gemm_bf16<0><<<(MROWS / 128) * (KDIM / 128), 256, 0, stream>>>(
        bufb, wtp, b_proj, out, MROWS, KDIM, KDIM, KDIM / 128);
}